// Round 4
// baseline (459.757 us; speedup 1.0000x reference)
//
#include <hip/hip_runtime.h>
#include <stdint.h>

// Problem constants
#define NDM   1024   // D_MODEL
#define NDS   16     // D_STATE
#define NDC   4      // D_CONV
#define NDI   2048   // D_INNER
#define NB    2      // BATCH
#define NL    2048   // SEQ
#define MROWS (NB*NL)   // 4096
#define CCH   32     // scan chunks  (scratch = NB*NDI*CCH*NDS*4 = 8.39MB each)
#define CLEN  64     // NL / CCH

typedef __bf16 bf16x8 __attribute__((ext_vector_type(8)));
typedef float  f32x4  __attribute__((ext_vector_type(4)));

__device__ __forceinline__ short f2bf(float f) {
  union { float f; unsigned u; } x; x.f = f;
  unsigned r = (x.u + 0x7FFFu + ((x.u >> 16) & 1u)) >> 16;
  return (short)r;
}

__device__ __forceinline__ void gload16(const void* g, void* l) {
  __builtin_amdgcn_global_load_lds(
      (__attribute__((address_space(1))) void*)(uintptr_t)g,
      (__attribute__((address_space(3))) void*)l,
      16, 0, 0);
}

// ---------------------------------------------------------------------------
// f32 -> bf16 elementwise convert
__global__ __launch_bounds__(256) void cvt_bf16_kernel(
    const float* __restrict__ in, short* __restrict__ out, int n) {
  int i = blockIdx.x * 256 + threadIdx.x;
  if (i < n) out[i] = f2bf(in[i]);
}

// ---------------------------------------------------------------------------
// (K,N) f32  ->  (N,K) bf16 transpose (32x32 LDS tiles)
__global__ __launch_bounds__(256) void transpose_bf16_kernel(
    const float* __restrict__ in, short* __restrict__ out, int K, int N) {
  __shared__ float t[32][33];
  const int tx = threadIdx.x, ty = threadIdx.y;   // 32, 8
  const int n0 = blockIdx.x * 32, k0 = blockIdx.y * 32;
  #pragma unroll
  for (int i = 0; i < 32; i += 8)
    t[ty + i][tx] = in[(size_t)(k0 + ty + i) * N + n0 + tx];
  __syncthreads();
  #pragma unroll
  for (int i = 0; i < 32; i += 8)
    out[(size_t)(n0 + ty + i) * K + k0 + tx] = f2bf(t[tx][ty + i]);
}

// ---------------------------------------------------------------------------
// bf16 TN GEMM: C(MxN,f32) = A(MxK,bf16) * Bt(NxK,bf16)^T + bias
// EPI: 0 = bias only, 1 = softplus(v + bias)
// BMxBN tile, BK=32, 4 waves (2x2), 16x16x32 MFMA, fragment-major LDS.
// BM,BN in {64,128}: per-wave tile (BM/2)x(BN/2).
template<int BM, int BN, int EPI>
__global__ __launch_bounds__(256) void gemm_bf16_kernel(
    const short* __restrict__ A, const short* __restrict__ Bt,
    const float* __restrict__ bias, float* __restrict__ C,
    int M, int N, int K)
{
  const int tid  = threadIdx.x;
  const int lane = tid & 63;
  const int w    = tid >> 6;      // wave 0..3
  const int wM   = w >> 1;
  const int wN   = w & 1;
  const int g    = lane >> 4;     // k-group 0..3
  const int r    = lane & 15;     // row/col within fragment

  const int bm = blockIdx.y * BM;
  const int bn = blockIdx.x * BN;

  constexpr int FM  = BM / 32;    // A fragments per wave
  constexpr int FN  = BN / 32;    // B fragments per wave
  constexpr int QA  = BM / 64;    // A staging groups per wave
  constexpr int QB  = BN / 64;    // B staging groups per wave

  // fragment-major: element idx = R*512 + lane*8  (R = 16-row group)
  __shared__ short lA[BM * 32];
  __shared__ short lB[BN * 32];

  f32x4 acc[FM][FN];
  #pragma unroll
  for (int m = 0; m < FM; ++m)
    #pragma unroll
    for (int n = 0; n < FN; ++n)
      acc[m][n] = (f32x4){0.f, 0.f, 0.f, 0.f};

  const short* gA[QA];
  const short* gB[QB];
  #pragma unroll
  for (int q = 0; q < QA; ++q)
    gA[q] = A + (size_t)(bm + (w * QA + q) * 16 + r) * K + g * 8;
  #pragma unroll
  for (int q = 0; q < QB; ++q)
    gB[q] = Bt + (size_t)(bn + (w * QB + q) * 16 + r) * K + g * 8;

  for (int kb = 0; kb < K; kb += 32) {
    __syncthreads();                 // previous tile fully consumed
    #pragma unroll
    for (int q = 0; q < QA; ++q)
      gload16(gA[q] + kb, &lA[(w * QA + q) * 512]);
    #pragma unroll
    for (int q = 0; q < QB; ++q)
      gload16(gB[q] + kb, &lB[(w * QB + q) * 512]);
    __syncthreads();                 // staging complete (vmcnt drained)

    bf16x8 af[FM], bfv[FN];
    #pragma unroll
    for (int m = 0; m < FM; ++m)
      af[m] = *(const bf16x8*)&lA[(wM * FM + m) * 512 + lane * 8];
    #pragma unroll
    for (int n = 0; n < FN; ++n)
      bfv[n] = *(const bf16x8*)&lB[(wN * FN + n) * 512 + lane * 8];

    #pragma unroll
    for (int m = 0; m < FM; ++m)
      #pragma unroll
      for (int n = 0; n < FN; ++n)
        acc[m][n] = __builtin_amdgcn_mfma_f32_16x16x32_bf16(
            af[m], bfv[n], acc[m][n], 0, 0, 0);
  }

  // D layout (verified m89/m91): col = lane&15, row = (lane>>4)*4 + e
  #pragma unroll
  for (int m = 0; m < FM; ++m) {
    const int row0 = bm + wM * (BM / 2) + m * 16 + g * 4;
    #pragma unroll
    for (int n = 0; n < FN; ++n) {
      const int col = bn + wN * (BN / 2) + n * 16 + r;
      const float bv = bias[col];
      #pragma unroll
      for (int e = 0; e < 4; ++e) {
        float v = acc[m][n][e] + bv;
        if (EPI == 1) v = (v > 15.f) ? v : log1pf(__expf(v));
        C[(size_t)(row0 + e) * N + col] = v;
      }
    }
  }
}

// ---------------------------------------------------------------------------
// depthwise causal conv (width 4) + bias + SiLU; writes f32 and bf16 copies
__global__ __launch_bounds__(256) void conv_silu_kernel(
    const float* __restrict__ xz, const float* __restrict__ cw,
    const float* __restrict__ cb, float* __restrict__ xh,
    short* __restrict__ xhbf) {
  int idx = blockIdx.x * 256 + threadIdx.x;      // (b,t,c) over 2*2048*2048
  int c = idx & (NDI - 1);
  int t = (idx >> 11) & (NL - 1);
  int b = idx >> 22;
  const float* base = xz + ((size_t)b * NL) * (2 * NDI);
  float acc = cb[c];
  #pragma unroll
  for (int k = 0; k < NDC; ++k) {
    int tt = t - (NDC - 1) + k;
    if (tt >= 0) acc += cw[c * NDC + k] * base[(size_t)tt * (2 * NDI) + c];
  }
  float s = acc / (1.f + __expf(-acc));
  xh[idx] = s;
  xhbf[idx] = f2bf(s);
}

// ---------------------------------------------------------------------------
// Bmat[row, s] = sum_c xh[row,c] * W_x[c, 16+s] + b_x[16+s]; one wave per row
__global__ __launch_bounds__(256) void bmat_kernel(
    const float* __restrict__ xh, const float* __restrict__ Wx,
    const float* __restrict__ bx, float* __restrict__ Bm) {
  const int row  = blockIdx.x * 4 + (threadIdx.x >> 6);
  const int lane = threadIdx.x & 63;
  const int s = lane & 15, q = lane >> 4;
  const float* xr = xh + (size_t)row * NDI;
  float acc = 0.f;
  for (int c = q * 512; c < (q + 1) * 512; ++c)
    acc += xr[c] * Wx[c * (2 * NDS) + NDS + s];
  acc += __shfl_xor(acc, 16);
  acc += __shfl_xor(acc, 32);
  if (lane < 16) Bm[(size_t)row * NDS + s] = acc + bx[NDS + s];
}

// ---------------------------------------------------------------------------
// Chunked selective scan, phase 1: thread = (b, c, chunk); all 16 states in
// registers. Computes P_s = prod(dA_s) and hend_s (local scan, h_in = 0).
__global__ __launch_bounds__(256) void scan_p1_kernel(
    const float* __restrict__ delta, const float* __restrict__ Bm,
    const float* __restrict__ xh, const float* __restrict__ A_log,
    float* __restrict__ Pbuf, float* __restrict__ Hend) {
  const int i = blockIdx.x * 256 + threadIdx.x;     // NB*CCH*NDI
  const int c = i & (NDI - 1);
  const int k = (i >> 11) & (CCH - 1);
  const int b = i >> 16;                            // 11 + 5 bits
  const int t0 = k * CLEN;

  float Av[NDS];
  #pragma unroll
  for (int s = 0; s < NDS; ++s) Av[s] = -__expf(A_log[c * NDS + s]);

  const float* dp = delta + ((size_t)(b * NL + t0)) * NDI + c;
  const float* up = xh    + ((size_t)(b * NL + t0)) * NDI + c;
  const f32x4* Bp = (const f32x4*)(Bm + ((size_t)(b * NL + t0)) * NDS);

  float h[NDS], P[NDS];
  #pragma unroll
  for (int s = 0; s < NDS; ++s) { h[s] = 0.f; P[s] = 1.f; }

  #pragma unroll 4
  for (int j = 0; j < CLEN; ++j) {
    const float d = dp[(size_t)j * NDI];
    const float u = up[(size_t)j * NDI];
    f32x4 B0 = Bp[j * 4 + 0], B1 = Bp[j * 4 + 1];
    f32x4 B2 = Bp[j * 4 + 2], B3 = Bp[j * 4 + 3];
    const float du = d * u;
    float Bv[NDS];
    #pragma unroll
    for (int e = 0; e < 4; ++e) {
      Bv[e] = B0[e]; Bv[4 + e] = B1[e]; Bv[8 + e] = B2[e]; Bv[12 + e] = B3[e];
    }
    #pragma unroll
    for (int s = 0; s < NDS; ++s) {
      float dA = __expf(d * Av[s]);
      h[s] = dA * h[s] + du * Bv[s];
      P[s] *= dA;
    }
  }

  const size_t base = (((size_t)b * NDI + c) * CCH + k) * NDS;
  #pragma unroll
  for (int q = 0; q < 4; ++q) {
    *(f32x4*)&Pbuf[base + q * 4] = (f32x4){P[q*4], P[q*4+1], P[q*4+2], P[q*4+3]};
    *(f32x4*)&Hend[base + q * 4] = (f32x4){h[q*4], h[q*4+1], h[q*4+2], h[q*4+3]};
  }
}

// ---------------------------------------------------------------------------
// phase 2: thread = (b, c, s); serial combine across the chunks.
__global__ __launch_bounds__(256) void scan_p2_kernel(
    const float* __restrict__ Pbuf, const float* __restrict__ Hend,
    float* __restrict__ Hin) {
  const int i = blockIdx.x * 256 + threadIdx.x;     // 65536
  const int s = i & (NDS - 1);
  const int c = (i >> 4) & (NDI - 1);
  const int b = i >> 15;
  const size_t base = ((size_t)b * NDI + c) * CCH * NDS + s;
  float h = 0.f;
  #pragma unroll 8
  for (int k = 0; k < CCH; ++k) {
    Hin[base + (size_t)k * NDS] = h;
    h = Hend[base + (size_t)k * NDS] + Pbuf[base + (size_t)k * NDS] * h;
  }
}

// ---------------------------------------------------------------------------
// phase 3 + merge: rescan from h_in; y = (sum_s h + u*D) * silu(z) -> bf16
__global__ __launch_bounds__(256) void scan_p3_kernel(
    const float* __restrict__ delta, const float* __restrict__ Bm,
    const float* __restrict__ xh, const float* __restrict__ A_log,
    const float* __restrict__ Hin, const float* __restrict__ Dvec,
    const float* __restrict__ xz, short* __restrict__ ybf) {
  const int i = blockIdx.x * 256 + threadIdx.x;
  const int c = i & (NDI - 1);
  const int k = (i >> 11) & (CCH - 1);
  const int b = i >> 16;
  const int t0 = k * CLEN;

  float Av[NDS];
  #pragma unroll
  for (int s = 0; s < NDS; ++s) Av[s] = -__expf(A_log[c * NDS + s]);
  const float dcoef = Dvec[c];

  const float* dp = delta + ((size_t)(b * NL + t0)) * NDI + c;
  const float* up = xh    + ((size_t)(b * NL + t0)) * NDI + c;
  const f32x4* Bp = (const f32x4*)(Bm + ((size_t)(b * NL + t0)) * NDS);
  const float* zp = xz    + ((size_t)(b * NL + t0)) * (2 * NDI) + NDI + c;
  short* yp       = ybf   + ((size_t)(b * NL + t0)) * NDI + c;

  const size_t base = (((size_t)b * NDI + c) * CCH + k) * NDS;
  float h[NDS];
  #pragma unroll
  for (int s = 0; s < NDS; ++s) h[s] = Hin[base + s];

  #pragma unroll 4
  for (int j = 0; j < CLEN; ++j) {
    const float d = dp[(size_t)j * NDI];
    const float u = up[(size_t)j * NDI];
    f32x4 B0 = Bp[j * 4 + 0], B1 = Bp[j * 4 + 1];
    f32x4 B2 = Bp[j * 4 + 2], B3 = Bp[j * 4 + 3];
    const float du = d * u;
    float Bv[NDS];
    #pragma unroll
    for (int e = 0; e < 4; ++e) {
      Bv[e] = B0[e]; Bv[4 + e] = B1[e]; Bv[8 + e] = B2[e]; Bv[12 + e] = B3[e];
    }
    #pragma unroll
    for (int s = 0; s < NDS; ++s) {
      float dA = __expf(d * Av[s]);
      h[s] = dA * h[s] + du * Bv[s];
    }
    // register add-tree over the 16 states
    float sum01 = 0.f, sum23 = 0.f;
    #pragma unroll
    for (int s = 0; s < 8; ++s)  sum01 += h[s];
    #pragma unroll
    for (int s = 8; s < 16; ++s) sum23 += h[s];
    float y = sum01 + sum23 + u * dcoef;
    float z = zp[(size_t)j * (2 * NDI)];
    y *= z / (1.f + __expf(-z));
    yp[(size_t)j * NDI] = f2bf(y);
  }
}

// ---------------------------------------------------------------------------
extern "C" void kernel_launch(void* const* d_in, const int* in_sizes, int n_in,
                              void* d_out, int out_size, void* d_ws, size_t ws_size,
                              hipStream_t stream) {
  const float* x      = (const float*)d_in[0];
  const float* W_in   = (const float*)d_in[1];
  const float* b_in   = (const float*)d_in[2];
  const float* conv_w = (const float*)d_in[3];
  const float* conv_b = (const float*)d_in[4];
  const float* W_x    = (const float*)d_in[5];
  const float* b_x    = (const float*)d_in[6];
  const float* W_dt   = (const float*)d_in[7];
  const float* b_dt   = (const float*)d_in[8];
  const float* A_log  = (const float*)d_in[9];
  const float* Dv     = (const float*)d_in[10];
  const float* W_out  = (const float*)d_in[11];
  const float* b_out  = (const float*)d_in[12];
  float* out = (float*)d_out;

  char* w = (char*)d_ws;
  short* xbf   = (short*)(w);                  // 4096x1024 bf16   8.39MB
  short* WtIn  = (short*)(w + 8388608);        // 4096x1024 bf16   8.39MB
  short* WtDt  = (short*)(w + 16777216);       // 2048x2048 bf16   8.39MB
  short* WtOut = (short*)(w + 25165824);       // 1024x2048 bf16   4.19MB
  float* xz    = (float*)(w + 29360128);       // 4096x4096 f32   67.1MB
  float* xhf   = (float*)(w + 96468992);       // 4096x2048 f32   33.6MB
  short* xhbf  = (short*)(w + 130023424);      // 4096x2048 bf16  16.8MB
  float* delta = (float*)(w + 146800640);      // 4096x2048 f32   33.6MB
  float* Bm    = (float*)(w + 180355072);      // 4096x16   f32    0.26MB
  short* ybf   = (short*)(w + 214171648);      // 4096x2048 bf16  16.8MB
  // scan scratch aliases buffers that are dead by scan time.
  // Each is NB*NDI*CCH*NDS*4 = 8.39MB with CCH=32 -> the three fit exactly
  // in [0, 25165824) (xbf+WtIn+WtDt region), not touching WtOut/xz.
  float* Pbuf  = (float*)(w);                  // aliases xbf  (8.39MB)
  float* Hend  = (float*)(w + 8388608);        // aliases WtIn (8.39MB)
  float* Hin   = (float*)(w + 16777216);       // aliases WtDt (8.39MB)

  // 1) converts / weight transposes (K,N)->(N,K) bf16
  cvt_bf16_kernel<<<(MROWS * NDM) / 256, 256, 0, stream>>>(x, xbf, MROWS * NDM);
  transpose_bf16_kernel<<<dim3((2 * NDI) / 32, NDM / 32), dim3(32, 8), 0, stream>>>(
      W_in, WtIn, NDM, 2 * NDI);
  transpose_bf16_kernel<<<dim3(NDI / 32, NDI / 32), dim3(32, 8), 0, stream>>>(
      W_dt, WtDt, NDI, NDI);
  transpose_bf16_kernel<<<dim3(NDM / 32, NDI / 32), dim3(32, 8), 0, stream>>>(
      W_out, WtOut, NDI, NDM);

  // 2) xz = x @ W_in + b_in   (128x128 tile: 1024 blocks, 4/CU)
  gemm_bf16_kernel<128, 128, 0><<<dim3((2 * NDI) / 128, MROWS / 128), 256, 0, stream>>>(
      xbf, WtIn, b_in, xz, MROWS, 2 * NDI, NDM);

  // 3) depthwise conv + silu
  conv_silu_kernel<<<(MROWS * NDI) / 256, 256, 0, stream>>>(
      xz, conv_w, conv_b, xhf, xhbf);

  // 4) Bmat = xh @ W_x[:,16:32] + b_x[16:32]
  bmat_kernel<<<MROWS / 4, 256, 0, stream>>>(xhf, W_x, b_x, Bm);

  // 5) delta = softplus(xh @ W_dt + b_dt)   (128x64 tile: 1024 blocks, 4/CU)
  gemm_bf16_kernel<128, 64, 1><<<dim3(NDI / 64, MROWS / 128), 256, 0, stream>>>(
      xhbf, WtDt, b_dt, delta, MROWS, NDI, NDI);

  // 6) selective scan (chunked: local scan -> chunk combine -> rescan+merge)
  scan_p1_kernel<<<(NB * NDI * CCH) / 256, 256, 0, stream>>>(
      delta, Bm, xhf, A_log, Pbuf, Hend);
  scan_p2_kernel<<<(NB * NDI * NDS) / 256, 256, 0, stream>>>(Pbuf, Hend, Hin);
  scan_p3_kernel<<<(NB * NDI * CCH) / 256, 256, 0, stream>>>(
      delta, Bm, xhf, A_log, Hin, Dv, xz, ybf);

  // 7) out = y @ W_out + b_out   (128x64 tile: 512 blocks, 2/CU)
  gemm_bf16_kernel<128, 64, 0><<<dim3(NDM / 64, MROWS / 128), 256, 0, stream>>>(
      ybf, WtOut, b_out, out, MROWS, NDM, NDI);
}

// Round 5
// 418.015 us; speedup vs baseline: 1.0999x; 1.0999x over previous
//
#include <hip/hip_runtime.h>
#include <stdint.h>

// Problem constants
#define NDM   1024   // D_MODEL
#define NDS   16     // D_STATE
#define NDC   4      // D_CONV
#define NDI   2048   // D_INNER
#define NB    2      // BATCH
#define NL    2048   // SEQ
#define MROWS (NB*NL)   // 4096
#define CCH   32     // scan chunks  (scratch = NB*NDI*CCH*NDS*4 = 8.39MB each)
#define CLEN  64     // NL / CCH

typedef __bf16 bf16x8 __attribute__((ext_vector_type(8)));
typedef float  f32x4  __attribute__((ext_vector_type(4)));

__device__ __forceinline__ short f2bf(float f) {
  union { float f; unsigned u; } x; x.f = f;
  unsigned r = (x.u + 0x7FFFu + ((x.u >> 16) & 1u)) >> 16;
  return (short)r;
}

__device__ __forceinline__ void gload16(const void* g, void* l) {
  __builtin_amdgcn_global_load_lds(
      (__attribute__((address_space(1))) void*)(uintptr_t)g,
      (__attribute__((address_space(3))) void*)l,
      16, 0, 0);
}

// ---------------------------------------------------------------------------
// f32 -> bf16 elementwise convert
__global__ __launch_bounds__(256) void cvt_bf16_kernel(
    const float* __restrict__ in, short* __restrict__ out, int n) {
  int i = blockIdx.x * 256 + threadIdx.x;
  if (i < n) out[i] = f2bf(in[i]);
}

// ---------------------------------------------------------------------------
// (K,N) f32  ->  (N,K) bf16 transpose (32x32 LDS tiles)
__global__ __launch_bounds__(256) void transpose_bf16_kernel(
    const float* __restrict__ in, short* __restrict__ out, int K, int N) {
  __shared__ float t[32][33];
  const int tx = threadIdx.x, ty = threadIdx.y;   // 32, 8
  const int n0 = blockIdx.x * 32, k0 = blockIdx.y * 32;
  #pragma unroll
  for (int i = 0; i < 32; i += 8)
    t[ty + i][tx] = in[(size_t)(k0 + ty + i) * N + n0 + tx];
  __syncthreads();
  #pragma unroll
  for (int i = 0; i < 32; i += 8)
    out[(size_t)(n0 + ty + i) * K + k0 + tx] = f2bf(t[tx][ty + i]);
}

// ---------------------------------------------------------------------------
// Pipelined bf16 TN GEMM: C(MxN,f32) = A(MxK,bf16) * Bt(NxK,bf16)^T + bias
// EPI: 0 = bias only, 1 = softplus(v + bias)
// 128x128 tile, BK=64, 8 waves (2Mx4N, per-wave 64x32), LDS double-buffer,
// ONE __syncthreads per K-step; next-tile global_load_lds issued right after
// the barrier so HBM latency hides under the current tile's 128 MFMAs.
template<int EPI>
__global__ __launch_bounds__(512, 4) void gemm_pipe_kernel(
    const short* __restrict__ A, const short* __restrict__ Bt,
    const float* __restrict__ bias, float* __restrict__ C,
    int M, int N, int K)
{
  const int tid  = threadIdx.x;
  const int lane = tid & 63;
  const int w    = tid >> 6;      // wave 0..7
  const int wM   = w >> 2;        // 0..1
  const int wN   = w & 3;         // 0..3
  const int g    = lane >> 4;     // k-group 0..3
  const int r    = lane & 15;     // row/col within fragment

  const int bm = blockIdx.y * 128;
  const int bn = blockIdx.x * 128;

  // fragment-major: slot (R=16-row group 0..7, kk=0..1) -> 512 shorts (1KB),
  // element = slot*512 + lane*8.  Wave w stages its own R=w slot pair.
  __shared__ short sA[2][8192];   // [buf][slot*512 + lane*8]  16KB per buf
  __shared__ short sB[2][8192];

  f32x4 acc[4][2];
  #pragma unroll
  for (int m = 0; m < 4; ++m)
    #pragma unroll
    for (int n = 0; n < 2; ++n)
      acc[m][n] = (f32x4){0.f, 0.f, 0.f, 0.f};

  const short* gA = A  + (size_t)(bm + w * 16 + r) * K + g * 8;
  const short* gB = Bt + (size_t)(bn + w * 16 + r) * K + g * 8;

#define STAGE(buf, kb)                                              \
  do {                                                              \
    gload16(gA + (kb),      &sA[buf][w * 1024 +       lane * 8]);   \
    gload16(gA + (kb) + 32, &sA[buf][w * 1024 + 512 + lane * 8]);   \
    gload16(gB + (kb),      &sB[buf][w * 1024 +       lane * 8]);   \
    gload16(gB + (kb) + 32, &sB[buf][w * 1024 + 512 + lane * 8]);   \
  } while (0)

  STAGE(0, 0);
  int cur = 0;
  for (int kb = 0; kb < K; kb += 64) {
    __syncthreads();               // drains own vmcnt -> all stages into cur
                                   // done; also prev compute done reading cur^1
    if (kb + 64 < K) STAGE(cur ^ 1, kb + 64);   // prefetch next tile

    bf16x8 af[4][2], bfv[2][2];
    #pragma unroll
    for (int m = 0; m < 4; ++m)
      #pragma unroll
      for (int kk = 0; kk < 2; ++kk)
        af[m][kk] = *(const bf16x8*)&sA[cur][((wM * 4 + m) * 2 + kk) * 512 + lane * 8];
    #pragma unroll
    for (int n = 0; n < 2; ++n)
      #pragma unroll
      for (int kk = 0; kk < 2; ++kk)
        bfv[n][kk] = *(const bf16x8*)&sB[cur][((wN * 2 + n) * 2 + kk) * 512 + lane * 8];

    #pragma unroll
    for (int kk = 0; kk < 2; ++kk)
      #pragma unroll
      for (int m = 0; m < 4; ++m)
        #pragma unroll
        for (int n = 0; n < 2; ++n)
          acc[m][n] = __builtin_amdgcn_mfma_f32_16x16x32_bf16(
              af[m][kk], bfv[n][kk], acc[m][n], 0, 0, 0);
    cur ^= 1;
  }
#undef STAGE

  // D layout (verified m89/m91): col = lane&15, row = (lane>>4)*4 + e
  #pragma unroll
  for (int m = 0; m < 4; ++m) {
    const int row0 = bm + wM * 64 + m * 16 + g * 4;
    #pragma unroll
    for (int n = 0; n < 2; ++n) {
      const int col = bn + wN * 32 + n * 16 + r;
      const float bv = bias[col];
      #pragma unroll
      for (int e = 0; e < 4; ++e) {
        float v = acc[m][n][e] + bv;
        if (EPI == 1) v = (v > 15.f) ? v : log1pf(__expf(v));
        C[(size_t)(row0 + e) * N + col] = v;
      }
    }
  }
}

// ---------------------------------------------------------------------------
// depthwise causal conv (width 4) + bias + SiLU; writes f32 and bf16 copies
__global__ __launch_bounds__(256) void conv_silu_kernel(
    const float* __restrict__ xz, const float* __restrict__ cw,
    const float* __restrict__ cb, float* __restrict__ xh,
    short* __restrict__ xhbf) {
  int idx = blockIdx.x * 256 + threadIdx.x;      // (b,t,c) over 2*2048*2048
  int c = idx & (NDI - 1);
  int t = (idx >> 11) & (NL - 1);
  int b = idx >> 22;
  const float* base = xz + ((size_t)b * NL) * (2 * NDI);
  float acc = cb[c];
  #pragma unroll
  for (int k = 0; k < NDC; ++k) {
    int tt = t - (NDC - 1) + k;
    if (tt >= 0) acc += cw[c * NDC + k] * base[(size_t)tt * (2 * NDI) + c];
  }
  float s = acc / (1.f + __expf(-acc));
  xh[idx] = s;
  xhbf[idx] = f2bf(s);
}

// ---------------------------------------------------------------------------
// Bmat[row, s] = sum_c xh[row,c] * W_x[c, 16+s] + b_x[16+s]; one wave per row
__global__ __launch_bounds__(256) void bmat_kernel(
    const float* __restrict__ xh, const float* __restrict__ Wx,
    const float* __restrict__ bx, float* __restrict__ Bm) {
  const int row  = blockIdx.x * 4 + (threadIdx.x >> 6);
  const int lane = threadIdx.x & 63;
  const int s = lane & 15, q = lane >> 4;
  const float* xr = xh + (size_t)row * NDI;
  float acc = 0.f;
  for (int c = q * 512; c < (q + 1) * 512; ++c)
    acc += xr[c] * Wx[c * (2 * NDS) + NDS + s];
  acc += __shfl_xor(acc, 16);
  acc += __shfl_xor(acc, 32);
  if (lane < 16) Bm[(size_t)row * NDS + s] = acc + bx[NDS + s];
}

// ---------------------------------------------------------------------------
// Chunked selective scan, phase 1: thread = (b, c, chunk); all 16 states in
// registers. Computes P_s = prod(dA_s) and hend_s (local scan, h_in = 0).
__global__ __launch_bounds__(256) void scan_p1_kernel(
    const float* __restrict__ delta, const float* __restrict__ Bm,
    const float* __restrict__ xh, const float* __restrict__ A_log,
    float* __restrict__ Pbuf, float* __restrict__ Hend) {
  const int i = blockIdx.x * 256 + threadIdx.x;     // NB*CCH*NDI
  const int c = i & (NDI - 1);
  const int k = (i >> 11) & (CCH - 1);
  const int b = i >> 16;                            // 11 + 5 bits
  const int t0 = k * CLEN;

  float Av[NDS];
  #pragma unroll
  for (int s = 0; s < NDS; ++s) Av[s] = -__expf(A_log[c * NDS + s]);

  const float* dp = delta + ((size_t)(b * NL + t0)) * NDI + c;
  const float* up = xh    + ((size_t)(b * NL + t0)) * NDI + c;
  const f32x4* Bp = (const f32x4*)(Bm + ((size_t)(b * NL + t0)) * NDS);

  float h[NDS], P[NDS];
  #pragma unroll
  for (int s = 0; s < NDS; ++s) { h[s] = 0.f; P[s] = 1.f; }

  #pragma unroll 4
  for (int j = 0; j < CLEN; ++j) {
    const float d = dp[(size_t)j * NDI];
    const float u = up[(size_t)j * NDI];
    f32x4 B0 = Bp[j * 4 + 0], B1 = Bp[j * 4 + 1];
    f32x4 B2 = Bp[j * 4 + 2], B3 = Bp[j * 4 + 3];
    const float du = d * u;
    float Bv[NDS];
    #pragma unroll
    for (int e = 0; e < 4; ++e) {
      Bv[e] = B0[e]; Bv[4 + e] = B1[e]; Bv[8 + e] = B2[e]; Bv[12 + e] = B3[e];
    }
    #pragma unroll
    for (int s = 0; s < NDS; ++s) {
      float dA = __expf(d * Av[s]);
      h[s] = dA * h[s] + du * Bv[s];
      P[s] *= dA;
    }
  }

  const size_t base = (((size_t)b * NDI + c) * CCH + k) * NDS;
  #pragma unroll
  for (int q = 0; q < 4; ++q) {
    *(f32x4*)&Pbuf[base + q * 4] = (f32x4){P[q*4], P[q*4+1], P[q*4+2], P[q*4+3]};
    *(f32x4*)&Hend[base + q * 4] = (f32x4){h[q*4], h[q*4+1], h[q*4+2], h[q*4+3]};
  }
}

// ---------------------------------------------------------------------------
// phase 2: thread = (b, c, s); serial combine across the chunks.
__global__ __launch_bounds__(256) void scan_p2_kernel(
    const float* __restrict__ Pbuf, const float* __restrict__ Hend,
    float* __restrict__ Hin) {
  const int i = blockIdx.x * 256 + threadIdx.x;     // 65536
  const int s = i & (NDS - 1);
  const int c = (i >> 4) & (NDI - 1);
  const int b = i >> 15;
  const size_t base = ((size_t)b * NDI + c) * CCH * NDS + s;
  float h = 0.f;
  #pragma unroll 8
  for (int k = 0; k < CCH; ++k) {
    Hin[base + (size_t)k * NDS] = h;
    h = Hend[base + (size_t)k * NDS] + Pbuf[base + (size_t)k * NDS] * h;
  }
}

// ---------------------------------------------------------------------------
// phase 3 + merge: rescan from h_in; y = (sum_s h + u*D) * silu(z) -> bf16
__global__ __launch_bounds__(256) void scan_p3_kernel(
    const float* __restrict__ delta, const float* __restrict__ Bm,
    const float* __restrict__ xh, const float* __restrict__ A_log,
    const float* __restrict__ Hin, const float* __restrict__ Dvec,
    const float* __restrict__ xz, short* __restrict__ ybf) {
  const int i = blockIdx.x * 256 + threadIdx.x;
  const int c = i & (NDI - 1);
  const int k = (i >> 11) & (CCH - 1);
  const int b = i >> 16;
  const int t0 = k * CLEN;

  float Av[NDS];
  #pragma unroll
  for (int s = 0; s < NDS; ++s) Av[s] = -__expf(A_log[c * NDS + s]);
  const float dcoef = Dvec[c];

  const float* dp = delta + ((size_t)(b * NL + t0)) * NDI + c;
  const float* up = xh    + ((size_t)(b * NL + t0)) * NDI + c;
  const f32x4* Bp = (const f32x4*)(Bm + ((size_t)(b * NL + t0)) * NDS);
  const float* zp = xz    + ((size_t)(b * NL + t0)) * (2 * NDI) + NDI + c;
  short* yp       = ybf   + ((size_t)(b * NL + t0)) * NDI + c;

  const size_t base = (((size_t)b * NDI + c) * CCH + k) * NDS;
  float h[NDS];
  #pragma unroll
  for (int s = 0; s < NDS; ++s) h[s] = Hin[base + s];

  #pragma unroll 4
  for (int j = 0; j < CLEN; ++j) {
    const float d = dp[(size_t)j * NDI];
    const float u = up[(size_t)j * NDI];
    f32x4 B0 = Bp[j * 4 + 0], B1 = Bp[j * 4 + 1];
    f32x4 B2 = Bp[j * 4 + 2], B3 = Bp[j * 4 + 3];
    const float du = d * u;
    float Bv[NDS];
    #pragma unroll
    for (int e = 0; e < 4; ++e) {
      Bv[e] = B0[e]; Bv[4 + e] = B1[e]; Bv[8 + e] = B2[e]; Bv[12 + e] = B3[e];
    }
    #pragma unroll
    for (int s = 0; s < NDS; ++s) {
      float dA = __expf(d * Av[s]);
      h[s] = dA * h[s] + du * Bv[s];
    }
    // register add-tree over the 16 states
    float sum01 = 0.f, sum23 = 0.f;
    #pragma unroll
    for (int s = 0; s < 8; ++s)  sum01 += h[s];
    #pragma unroll
    for (int s = 8; s < 16; ++s) sum23 += h[s];
    float y = sum01 + sum23 + u * dcoef;
    float z = zp[(size_t)j * (2 * NDI)];
    y *= z / (1.f + __expf(-z));
    yp[(size_t)j * NDI] = f2bf(y);
  }
}

// ---------------------------------------------------------------------------
extern "C" void kernel_launch(void* const* d_in, const int* in_sizes, int n_in,
                              void* d_out, int out_size, void* d_ws, size_t ws_size,
                              hipStream_t stream) {
  const float* x      = (const float*)d_in[0];
  const float* W_in   = (const float*)d_in[1];
  const float* b_in   = (const float*)d_in[2];
  const float* conv_w = (const float*)d_in[3];
  const float* conv_b = (const float*)d_in[4];
  const float* W_x    = (const float*)d_in[5];
  const float* b_x    = (const float*)d_in[6];
  const float* W_dt   = (const float*)d_in[7];
  const float* b_dt   = (const float*)d_in[8];
  const float* A_log  = (const float*)d_in[9];
  const float* Dv     = (const float*)d_in[10];
  const float* W_out  = (const float*)d_in[11];
  const float* b_out  = (const float*)d_in[12];
  float* out = (float*)d_out;

  char* w = (char*)d_ws;
  short* xbf   = (short*)(w);                  // 4096x1024 bf16   8.39MB
  short* WtIn  = (short*)(w + 8388608);        // 4096x1024 bf16   8.39MB
  short* WtDt  = (short*)(w + 16777216);       // 2048x2048 bf16   8.39MB
  short* WtOut = (short*)(w + 25165824);       // 1024x2048 bf16   4.19MB
  float* xz    = (float*)(w + 29360128);       // 4096x4096 f32   67.1MB
  float* xhf   = (float*)(w + 96468992);       // 4096x2048 f32   33.6MB
  short* xhbf  = (short*)(w + 130023424);      // 4096x2048 bf16  16.8MB
  float* delta = (float*)(w + 146800640);      // 4096x2048 f32   33.6MB
  float* Bm    = (float*)(w + 180355072);      // 4096x16   f32    0.26MB
  short* ybf   = (short*)(w + 214171648);      // 4096x2048 bf16  16.8MB
  // scan scratch aliases buffers that are dead by scan time.
  // Each is NB*NDI*CCH*NDS*4 = 8.39MB with CCH=32 -> the three fit exactly
  // in [0, 25165824) (xbf+WtIn+WtDt region), not touching WtOut/xz.
  float* Pbuf  = (float*)(w);                  // aliases xbf  (8.39MB)
  float* Hend  = (float*)(w + 8388608);        // aliases WtIn (8.39MB)
  float* Hin   = (float*)(w + 16777216);       // aliases WtDt (8.39MB)

  // 1) converts / weight transposes (K,N)->(N,K) bf16
  cvt_bf16_kernel<<<(MROWS * NDM) / 256, 256, 0, stream>>>(x, xbf, MROWS * NDM);
  transpose_bf16_kernel<<<dim3((2 * NDI) / 32, NDM / 32), dim3(32, 8), 0, stream>>>(
      W_in, WtIn, NDM, 2 * NDI);
  transpose_bf16_kernel<<<dim3(NDI / 32, NDI / 32), dim3(32, 8), 0, stream>>>(
      W_dt, WtDt, NDI, NDI);
  transpose_bf16_kernel<<<dim3(NDM / 32, NDI / 32), dim3(32, 8), 0, stream>>>(
      W_out, WtOut, NDI, NDM);

  // 2) xz = x @ W_in + b_in   (32x32 = 1024 blocks)
  gemm_pipe_kernel<0><<<dim3((2 * NDI) / 128, MROWS / 128), 512, 0, stream>>>(
      xbf, WtIn, b_in, xz, MROWS, 2 * NDI, NDM);

  // 3) depthwise conv + silu
  conv_silu_kernel<<<(MROWS * NDI) / 256, 256, 0, stream>>>(
      xz, conv_w, conv_b, xhf, xhbf);

  // 4) Bmat = xh @ W_x[:,16:32] + b_x[16:32]
  bmat_kernel<<<MROWS / 4, 256, 0, stream>>>(xhf, W_x, b_x, Bm);

  // 5) delta = softplus(xh @ W_dt + b_dt)   (16x32 = 512 blocks)
  gemm_pipe_kernel<1><<<dim3(NDI / 128, MROWS / 128), 512, 0, stream>>>(
      xhbf, WtDt, b_dt, delta, MROWS, NDI, NDI);

  // 6) selective scan (chunked: local scan -> chunk combine -> rescan+merge)
  scan_p1_kernel<<<(NB * NDI * CCH) / 256, 256, 0, stream>>>(
      delta, Bm, xhf, A_log, Pbuf, Hend);
  scan_p2_kernel<<<(NB * NDI * NDS) / 256, 256, 0, stream>>>(Pbuf, Hend, Hin);
  scan_p3_kernel<<<(NB * NDI * CCH) / 256, 256, 0, stream>>>(
      delta, Bm, xhf, A_log, Hin, Dv, xz, ybf);

  // 7) out = y @ W_out + b_out   (8x32 = 256 blocks)
  gemm_pipe_kernel<0><<<dim3(NDM / 128, MROWS / 128), 512, 0, stream>>>(
      ybf, WtOut, b_out, out, MROWS, NDM, NDI);
}